// Round 4
// 17502.138 us; speedup vs baseline: 1.9577x; 1.9577x over previous
//
#include <hip/hip_runtime.h>
#include <stdint.h>

// ---------------- constants ----------------
#define NWG   128        // cooperative grid: 1 WG per CU
#define NTHR  256
#define Bsz   64
#define Tsz   512
#define Dsz   1024
#define Hsz   1024

typedef __attribute__((ext_vector_type(8))) short short8;      // 8 bf16 (4 VGPRs)
typedef __attribute__((ext_vector_type(4))) float f32x4;
typedef __attribute__((ext_vector_type(4))) unsigned uintx4;   // asm-legal 128b vector
                                                               // (HIP uint4 is a struct ->
                                                               //  "indirect register input")

__device__ __forceinline__ unsigned short f2bf(float f) {
    unsigned u = __builtin_bit_cast(unsigned, f);
    u += 0x7fffu + ((u >> 16) & 1u);          // RNE
    return (unsigned short)(u >> 16);
}
__device__ __forceinline__ float sigm(float x) {
    float e = __expf(-__builtin_fabsf(x));
    float r = 1.0f / (1.0f + e);
    return x >= 0.0f ? r : 1.0f - r;          // overflow-safe
}
__device__ __forceinline__ float tanh_(float x) {
    float e = __expf(-2.0f * __builtin_fabsf(x));
    float r = (1.0f - e) / (1.0f + e);
    return x >= 0.0f ? r : -r;                // overflow-safe
}

// ---- cross-XCD h state: LOADS via compiler (hazard-safe), STORES via asm ----
// Round-3 post-mortem: split asm {issue-load ... s_waitcnt} let the compiler
// copy/spill the load's DEST registers before the waitcnt (VMEM dest regs are
// NOT scoreboarded on CDNA) -> garbage z -> saturated gates -> c ramped to
// ~468.  Fix: h loads are __hip_atomic_load (RELAXED, AGENT): the compiler
// owns the waitcnt-before-use, so no register hazard is possible, and
// agent-scope atomics are emitted with L0/L2 bypass (LLC-coherent) without
// any cache invalidation -> per-XCD L2 stays weight-hot all 1024 steps.
__device__ __forceinline__ short8 ldh(const unsigned short* p) {
    unsigned long long lo = __hip_atomic_load((const unsigned long long*)p,
                                              __ATOMIC_RELAXED, __HIP_MEMORY_SCOPE_AGENT);
    unsigned long long hi = __hip_atomic_load((const unsigned long long*)p + 1,
                                              __ATOMIC_RELAXED, __HIP_MEMORY_SCOPE_AGENT);
    union { unsigned long long q[2]; short8 s; } u;
    u.q[0] = lo; u.q[1] = hi;
    return u.s;
}
// Stores read their operands at issue -> no dest-reg hazard -> asm is safe,
// and guarantees sc0 sc1 (write through to the LLC, never dirty any cache).
__device__ __forceinline__ void st16_cc(unsigned short* p, uintx4 v) {
    asm volatile("global_store_dwordx4 %0, %1, off sc0 sc1" :: "v"(p), "v"(v) : "memory");
}
__device__ __forceinline__ void st4_cc(unsigned* p, unsigned v) {
    asm volatile("global_store_dword %0, %1, off sc0 sc1" :: "v"(p), "v"(v) : "memory");
}
__device__ __forceinline__ void drain_vm() {
    asm volatile("s_waitcnt vmcnt(0)" ::: "memory");
}
__device__ __forceinline__ void bar_arrive(unsigned* bar) {
    unsigned one = 1u;
    asm volatile("global_atomic_add %0, %1, off sc1" :: "v"(bar), "v"(one) : "memory");
}
// poll's waitcnt is INSIDE the asm block -> output defined only after data
// arrival; no hazard.
__device__ __forceinline__ unsigned bar_poll(const unsigned* bar) {
    unsigned v;
    asm volatile("global_load_dword %0, %1, off sc0 sc1\n\t"
                 "s_waitcnt vmcnt(0)"
                 : "=&v"(v) : "v"(bar) : "memory");
    return v;
}

// ---------------- prep kernels ----------------
// x [B][T][D] f32  ->  xb [t][kb(128)][b(64)][8] bf16   (MFMA A-fragment-native)
__global__ void cast_x(const float* __restrict__ x, unsigned short* __restrict__ xb) {
    int o = blockIdx.x * 256 + threadIdx.x;       // 512*128*64 = 4,194,304
    int t = o >> 13;
    int r = o & 8191;
    int kb = r >> 6;
    int b  = r & 63;
    const float* s = x + (((size_t)b * Tsz + t) * Dsz + kb * 8);
    float4 f0 = ((const float4*)s)[0];
    float4 f1 = ((const float4*)s)[1];
    unsigned short tmp[8];
    tmp[0] = f2bf(f0.x); tmp[1] = f2bf(f0.y); tmp[2] = f2bf(f0.z); tmp[3] = f2bf(f0.w);
    tmp[4] = f2bf(f1.x); tmp[5] = f2bf(f1.y); tmp[6] = f2bf(f1.z); tmp[7] = f2bf(f1.w);
    ((uint4*)xb)[o] = *(const uint4*)tmp;
}

// W [2048][4096] f32 -> wc [w(128)][kb(256)][n(32)][8] bf16 in MFMA B-layout, columns permuted
__global__ void build_wc(const float* __restrict__ W0, const float* __restrict__ W1,
                         unsigned short* __restrict__ wc0, unsigned short* __restrict__ wc1) {
    int o = blockIdx.x * 256 + threadIdx.x;       // 2*128*256*32 = 2,097,152
    int layer = o >> 20;
    int r = o & 1048575;
    int w  = r >> 13;
    int r2 = r & 8191;
    int kb = r2 >> 5;
    int n  = r2 & 31;
    int nt = n >> 4, n16 = n & 15;
    int g = n16 >> 2, q = n16 & 3;
    int col = g * 1024 + w * 8 + nt * 4 + q;
    const float* W = layer ? W1 : W0;
    unsigned short* wc = layer ? wc1 : wc0;
    unsigned short tmp[8];
#pragma unroll
    for (int i = 0; i < 8; ++i) tmp[i] = f2bf(W[(size_t)(kb * 8 + i) * 4096 + col]);
    ((uint4*)wc)[r] = *(const uint4*)tmp;
}

// permuted biases pb[layer][w][32] f32, plus barrier state init (ws is poisoned each launch!)
__global__ void build_pb(const float* __restrict__ b0, const float* __restrict__ b1,
                         float* __restrict__ pb, unsigned* __restrict__ bar) {
    int o = blockIdx.x * 256 + threadIdx.x;       // 8192
    if (o < 2) bar[o] = 0u;
    int layer = o >> 12;
    int r = o & 4095;
    int w = r >> 5;
    int n = r & 31;
    int nt = n >> 4, n16 = n & 15;
    int g = n16 >> 2, q = n16 & 3;
    const float* bb = layer ? b1 : b0;
    pb[o] = bb[g * 1024 + w * 8 + nt * 4 + q];
}

// ---------------- grid barriers ----------------
// Monotonic counter at the LLC (asm sc1 atomics).  NO cache maintenance ->
// per-XCD L2 stays weight-hot across steps.  Data handoff contract: bypass
// stores drained (vmcnt 0) BEFORE arrival; bypass loads issued AFTER exit.
__device__ __forceinline__ void gbar_relaxed(unsigned* bar, unsigned& tgt) {
    __syncthreads();
    if (threadIdx.x == 0) {
        tgt += NWG;
        bar_arrive(bar);
        while (bar_poll(bar) < tgt) __builtin_amdgcn_s_sleep(2);
    }
    __syncthreads();
}
// Full-fence variant (L2 writeback + invalidate): ONLY at init and at the
// layer 0 -> layer 1 boundary, to publish normally-cached y0b.
__device__ __forceinline__ void gbar_full(unsigned* bar, unsigned& tgt) {
    __syncthreads();
    if (threadIdx.x == 0) {
        __threadfence();   // release: wb dirty L2 (y0b) -> LLC
        tgt += NWG;
        bar_arrive(bar);
        while (bar_poll(bar) < tgt) __builtin_amdgcn_s_sleep(2);
        __threadfence();   // acquire: inv L1/L2
    }
    __syncthreads();
}

// ---------------- pipelined 64x32x1024 GEMM slice ----------------
// Group-of-4 prefetch (depth 1).  BYP=true: A operand is the cross-XCD h
// buffer -> loads via ldh (compiler-managed hazards + LLC coherence).
template<bool BYP>
__device__ __forceinline__ void gemm_k1024(const unsigned short* __restrict__ a0p,
                                           const unsigned short* __restrict__ a1p,
                                           const unsigned short* __restrict__ b0p,
                                           const unsigned short* __restrict__ b1p,
                                           f32x4& c00, f32x4& c01, f32x4& c10, f32x4& c11) {
    short8 A0[2][4], A1[2][4], B0[2][4], B1[2][4];
#pragma unroll
    for (int i = 0; i < 4; ++i) {
        if constexpr (BYP) { A0[0][i] = ldh(a0p + i * 2048); A1[0][i] = ldh(a1p + i * 2048); }
        else { A0[0][i] = *(const short8*)(a0p + i * 2048); A1[0][i] = *(const short8*)(a1p + i * 2048); }
        B0[0][i] = *(const short8*)(b0p + i * 1024);
        B1[0][i] = *(const short8*)(b1p + i * 1024);
    }
#pragma unroll
    for (int g = 0; g < 8; ++g) {
        const int cur = g & 1, nxt = cur ^ 1;   // static after full unroll (rule #20 ok)
        if (g < 7) {
#pragma unroll
            for (int i = 0; i < 4; ++i) {
                const int s = (g + 1) * 4 + i;
                if constexpr (BYP) { A0[nxt][i] = ldh(a0p + s * 2048); A1[nxt][i] = ldh(a1p + s * 2048); }
                else { A0[nxt][i] = *(const short8*)(a0p + s * 2048); A1[nxt][i] = *(const short8*)(a1p + s * 2048); }
                B0[nxt][i] = *(const short8*)(b0p + s * 1024);
                B1[nxt][i] = *(const short8*)(b1p + s * 1024);
            }
        }
#pragma unroll
        for (int i = 0; i < 4; ++i) {
            c00 = __builtin_amdgcn_mfma_f32_16x16x32_bf16(A0[cur][i], B0[cur][i], c00, 0, 0, 0);
            c01 = __builtin_amdgcn_mfma_f32_16x16x32_bf16(A0[cur][i], B1[cur][i], c01, 0, 0, 0);
            c10 = __builtin_amdgcn_mfma_f32_16x16x32_bf16(A1[cur][i], B0[cur][i], c10, 0, 0, 0);
            c11 = __builtin_amdgcn_mfma_f32_16x16x32_bf16(A1[cur][i], B1[cur][i], c11, 0, 0, 0);
        }
    }
}

// ---------------- persistent LSTM loop ----------------
// xb  : [t][kb 0..127][b][8] bf16      (layer-0 x part of A; cached)
// y0b : same layout, layer-0 outputs   (layer-1 x part of A; published once at boundary)
// hb  : [2 bufs][kb2 0..127][b][8] bf16 (recurrent A; ONLY bypass-accessed, never cached)
// cst : [2 layers][j 0..1023][b] f32   (WG-private)
__launch_bounds__(NTHR, 1)
__global__ void lstm_loop(const unsigned short* __restrict__ xb,
                          unsigned short* __restrict__ y0b,
                          const unsigned short* __restrict__ wc0,
                          const unsigned short* __restrict__ wc1,
                          const float* __restrict__ pb,
                          const int* __restrict__ lens,
                          unsigned short* __restrict__ hb,
                          float* __restrict__ cst,
                          unsigned* __restrict__ bar,
                          float* __restrict__ out) {
    __shared__ float zbuf[2][64][33];   // [k-half][b][col32], +1 pad vs bank conflicts
    __shared__ float pbl[2][32];
    __shared__ __align__(16) unsigned short hsh[64][8];   // h staging: 256 ushort -> 64 dwordx4 stores

    const int w = blockIdx.x;
    const int tid = threadIdx.x;
    const int lane = tid & 63;
    const int wave = tid >> 6;
    const int m  = wave & 1;     // M-pair: rows [m*32, m*32+32)
    const int kh = wave >> 1;    // K-half: 0 = x part, 1 = h part
    const int q16 = lane >> 4;
    const int n16 = lane & 15;

    // ---- per-launch init (ws is re-poisoned every launch) ----
    st4_cc((unsigned*)hb + w * 256 + tid, 0u);                // zero hb buf0 slice (bypass!)
    {
        int ly = tid >> 7, r = tid & 127;                     // zero c state rows [8w,8w+8), both layers
        ((float4*)(cst + ly * 65536 + w * 512))[r] = make_float4(0.f, 0.f, 0.f, 0.f);
    }
    if (tid < 64) pbl[tid >> 5][tid & 31] = pb[((tid >> 5) * 128 + w) * 32 + (tid & 31)];
    const int lenb = lens[tid & 63];
    drain_vm();                                               // hb zeros at LLC before anyone reads
    unsigned tgt = 0;
    gbar_full(bar, tgt);

    for (int layer = 0; layer < 2; ++layer) {
        const unsigned short* xsrc = layer ? y0b : xb;
        const unsigned short* wc   = layer ? wc1 : wc0;
        int p = 0;
        float hpf[2] = {0.f, 0.f};   // this thread's own h(b, jj)/h(b, jj+4): hold-state source
        for (int t = 0; t < Tsz; ++t) {
            // ---- GEMM: z[64 x 32cols] += A[64 x 1024(kh)] * W[1024 x 32] ----
            f32x4 c00 = {0.f,0.f,0.f,0.f}, c01 = {0.f,0.f,0.f,0.f};
            f32x4 c10 = {0.f,0.f,0.f,0.f}, c11 = {0.f,0.f,0.f,0.f};
            const unsigned short* Abase = (kh == 0) ? (xsrc + (size_t)t * 65536)
                                                    : (hb + p * 65536);
            const int rowbase = m * 32 + n16;
            const unsigned short* a0p = Abase + (q16 * 64 + rowbase) * 8;
            const unsigned short* a1p = a0p + 128;                     // +16 rows
            const unsigned short* b0p = wc + w * 65536 + (kh * 128 + q16) * 256 + n16 * 8;
            const unsigned short* b1p = b0p + 128;                     // +16 cols
            if (kh == 0) gemm_k1024<false>(a0p, a1p, b0p, b1p, c00, c01, c10, c11);
            else         gemm_k1024<true >(a0p, a1p, b0p, b1p, c00, c01, c10, c11);
            {
                const int rowb = m * 32 + q16 * 4;
#pragma unroll
                for (int r = 0; r < 4; ++r) {
                    zbuf[kh][rowb + r][n16]           = c00[r];
                    zbuf[kh][rowb + r][n16 + 16]      = c01[r];
                    zbuf[kh][rowb + 16 + r][n16]      = c10[r];
                    zbuf[kh][rowb + 16 + r][n16 + 16] = c11[r];
                }
            }
            __syncthreads();

            // ---- elementwise gates + state update (this WG owns j = 8w..8w+7) ----
            const int b = tid & 63;
            const bool active = (t < lenb);
#pragma unroll
            for (int h2 = 0; h2 < 2; ++h2) {
                const int jj = wave + h2 * 4;
                const int nt = jj >> 2, qq = jj & 3;
                const int cb = nt * 16 + qq;
                float zi = zbuf[0][b][cb]      + zbuf[1][b][cb]      + pbl[layer][cb];
                float zc = zbuf[0][b][cb + 4]  + zbuf[1][b][cb + 4]  + pbl[layer][cb + 4];
                float zf = zbuf[0][b][cb + 8]  + zbuf[1][b][cb + 8]  + pbl[layer][cb + 8];
                float zo = zbuf[0][b][cb + 12] + zbuf[1][b][cb + 12] + pbl[layer][cb + 12];
                if (active) {
                    const int ci = (layer * 1024 + w * 8 + jj) * 64 + b;
                    float c  = cst[ci];
                    float cn = c * sigm(zf + 1.0f) + sigm(zi) * tanh_(zc);
                    cst[ci] = cn;
                    hpf[h2] = tanh_(cn) * sigm(zo);
                }  // inactive: hold hpf (dynamic_rnn state-hold), no hb read-back needed
                unsigned short hv = f2bf(hpf[h2]);
                hsh[b][jj] = hv;
                const int hi = (w * 64 + b) * 8 + jj;
                if (layer == 0) {
                    y0b[(size_t)t * 65536 + hi] = active ? hv : (unsigned short)0;
                } else {
                    out[(size_t)(b * Tsz + t) * 1024 + w * 8 + jj] = active ? hpf[h2] : 0.0f;
                }
            }
            __syncthreads();   // hsh complete
            if (tid < 64) {    // wave 0: publish this WG's h slice to LLC (bypass)
                uintx4 v = ((const uintx4*)hsh)[tid];
                st16_cc(hb + (size_t)(p ^ 1) * 65536 + (size_t)w * 512 + (size_t)tid * 8, v);
                drain_vm();    // h at LLC before arrival increment (thread 0 is in this wave)
            }
            gbar_relaxed(bar, tgt);
            p ^= 1;
        }
        // ---- final (h, c) stacks: straight from registers / private cst ----
        {
            const int b = tid & 63;
#pragma unroll
            for (int h2 = 0; h2 < 2; ++h2) {
                const int jj = wave + h2 * 4;
                const int j = w * 8 + jj;
                out[33554432 + layer * 65536 + b * 1024 + j]          = hpf[h2];                          // h_stack
                out[33554432 + 131072 + layer * 65536 + b * 1024 + j] = cst[(layer * 1024 + j) * 64 + b]; // c_stack
            }
        }
        if (layer == 0) {
            // re-zero hb buf0 (own slice) for layer 1 -- bypass stores, drained; then
            // full-fence barrier publishes the normally-cached y0b to layer 1.
            st4_cc((unsigned*)hb + w * 256 + tid, 0u);
            drain_vm();
            gbar_full(bar, tgt);
        }
    }
}

// ---------------- launcher ----------------
extern "C" void kernel_launch(void* const* d_in, const int* in_sizes, int n_in,
                              void* d_out, int out_size, void* d_ws, size_t ws_size,
                              hipStream_t stream) {
    const float* x    = (const float*)d_in[0];
    const int*   lens = (const int*)d_in[1];     // integer inputs arrive as int32
    const float* W0   = (const float*)d_in[2];
    const float* b0   = (const float*)d_in[3];
    const float* W1   = (const float*)d_in[4];
    const float* b1   = (const float*)d_in[5];
    char* ws = (char*)d_ws;

    unsigned short* xb  = (unsigned short*)(ws);                    //  67,108,864 B
    unsigned short* y0b = (unsigned short*)(ws + 67108864);         //  67,108,864 B
    unsigned short* wc0 = (unsigned short*)(ws + 134217728);        //  16,777,216 B
    unsigned short* wc1 = (unsigned short*)(ws + 150994944);        //  16,777,216 B
    float*          pb  = (float*)         (ws + 167772160);        //      32,768 B
    unsigned short* hb  = (unsigned short*)(ws + 167804928);        //     262,144 B
    float*          cst = (float*)         (ws + 168067072);        //     524,288 B
    unsigned*       bar = (unsigned*)      (ws + 168591360);        //         256 B

    hipLaunchKernelGGL(cast_x,   dim3(16384), dim3(256), 0, stream, x, xb);
    hipLaunchKernelGGL(build_wc, dim3(8192),  dim3(256), 0, stream, W0, W1, wc0, wc1);
    hipLaunchKernelGGL(build_pb, dim3(32),    dim3(256), 0, stream, b0, b1, pb, bar);

    float* out = (float*)d_out;
    void* args[] = { &xb, &y0b, &wc0, &wc1, &pb, &lens, &hb, &cst, &bar, &out };
    (void)hipLaunchCooperativeKernel((void*)lstm_loop, dim3(NWG), dim3(NTHR), args, 0, stream);
}

// Round 5
// 11529.593 us; speedup vs baseline: 2.9718x; 1.5180x over previous
//
#include <hip/hip_runtime.h>
#include <stdint.h>

// ---------------- constants ----------------
#define NWG   128        // cooperative grid: 1 WG per CU
#define NTHR  256
#define Tsz   512

typedef __attribute__((ext_vector_type(8))) short short8;      // 8 bf16 (4 VGPRs)
typedef __attribute__((ext_vector_type(4))) float f32x4;
typedef __attribute__((ext_vector_type(4))) unsigned uintx4;   // asm-legal 128b vector

__device__ __forceinline__ unsigned short f2bf(float f) {
    unsigned u = __builtin_bit_cast(unsigned, f);
    u += 0x7fffu + ((u >> 16) & 1u);          // RNE
    return (unsigned short)(u >> 16);
}
__device__ __forceinline__ float sigm(float x) {
    float e = __expf(-__builtin_fabsf(x));
    float r = 1.0f / (1.0f + e);
    return x >= 0.0f ? r : 1.0f - r;          // overflow-safe
}
__device__ __forceinline__ float tanh_(float x) {
    float e = __expf(-2.0f * __builtin_fabsf(x));
    float r = (1.0f - e) / (1.0f + e);
    return x >= 0.0f ? r : -r;                // overflow-safe
}

// ---- device-coherent asm primitives ----
// sc0 sc1 stores write through to the LLC (device coherence point); the
// written lines are NEVER dirty in any L1/L2.  Loads of ring slots use
// NORMAL cached loads: every ring address is write-once, read-only-after-
// barrier, so no cache can hold a stale copy (see ring comments below).
__device__ __forceinline__ void st16_cc(unsigned short* p, uintx4 v) {
    asm volatile("global_store_dwordx4 %0, %1, off sc0 sc1" :: "v"(p), "v"(v) : "memory");
}
__device__ __forceinline__ void st4_cc(unsigned* p, unsigned v) {
    asm volatile("global_store_dword %0, %1, off sc0 sc1" :: "v"(p), "v"(v) : "memory");
}
__device__ __forceinline__ void drain_vm() {
    asm volatile("s_waitcnt vmcnt(0)" ::: "memory");
}
// poll load: waitcnt INSIDE the asm block -> no dest-reg hazard (round-3 lesson)
__device__ __forceinline__ unsigned ld4_cc(const unsigned* p) {
    unsigned v;
    asm volatile("global_load_dword %0, %1, off sc0 sc1\n\t"
                 "s_waitcnt vmcnt(0)"
                 : "=&v"(v) : "v"(p) : "memory");
    return v;
}

// ---------------- prep kernels ----------------
// x [B][T][D] f32  ->  xb [t][kb(128)][b(64)][8] bf16   (MFMA A-fragment-native)
__global__ void cast_x(const float* __restrict__ x, unsigned short* __restrict__ xb) {
    int o = blockIdx.x * 256 + threadIdx.x;       // 512*128*64 = 4,194,304
    int t = o >> 13;
    int r = o & 8191;
    int kb = r >> 6;
    int b  = r & 63;
    const float* s = x + (((size_t)b * Tsz + t) * 1024 + kb * 8);
    float4 f0 = ((const float4*)s)[0];
    float4 f1 = ((const float4*)s)[1];
    unsigned short tmp[8];
    tmp[0] = f2bf(f0.x); tmp[1] = f2bf(f0.y); tmp[2] = f2bf(f0.z); tmp[3] = f2bf(f0.w);
    tmp[4] = f2bf(f1.x); tmp[5] = f2bf(f1.y); tmp[6] = f2bf(f1.z); tmp[7] = f2bf(f1.w);
    ((uint4*)xb)[o] = *(const uint4*)tmp;
}

// W [2048][4096] f32 -> wc [w(128)][kb(256)][n(32)][8] bf16 in MFMA B-layout, columns permuted
__global__ void build_wc(const float* __restrict__ W0, const float* __restrict__ W1,
                         unsigned short* __restrict__ wc0, unsigned short* __restrict__ wc1) {
    int o = blockIdx.x * 256 + threadIdx.x;       // 2*128*256*32 = 2,097,152
    int layer = o >> 20;
    int r = o & 1048575;
    int w  = r >> 13;
    int r2 = r & 8191;
    int kb = r2 >> 5;
    int n  = r2 & 31;
    int nt = n >> 4, n16 = n & 15;
    int g = n16 >> 2, q = n16 & 3;
    int col = g * 1024 + w * 8 + nt * 4 + q;
    const float* W = layer ? W1 : W0;
    unsigned short* wc = layer ? wc1 : wc0;
    unsigned short tmp[8];
#pragma unroll
    for (int i = 0; i < 8; ++i) tmp[i] = f2bf(W[(size_t)(kb * 8 + i) * 4096 + col]);
    ((uint4*)wc)[r] = *(const uint4*)tmp;
}

// permuted biases pb[layer][w][32] f32 + flag-barrier slots (ws poisoned each launch!)
__global__ void build_pb(const float* __restrict__ b0, const float* __restrict__ b1,
                         float* __restrict__ pb, unsigned* __restrict__ flg) {
    int o = blockIdx.x * 256 + threadIdx.x;       // 8192
    if (o < 2048) flg[o] = 0u;                    // 128 slots x 64B stride
    int layer = o >> 12;
    int r = o & 4095;
    int w = r >> 5;
    int n = r & 31;
    int nt = n >> 4, n16 = n & 15;
    int g = n16 >> 2, q = n16 & 3;
    const float* bb = layer ? b1 : b0;
    pb[o] = bb[g * 1024 + w * 8 + nt * 4 + q];
}

// ---------------- flat all-to-all flag barrier ----------------
// Each WG writes a monotonic seq number to its OWN 64B-strided slot (parallel
// stores, no atomic serialization); threads 0..127 each poll one slot.  No
// cache maintenance -> L2 stays hot.  Handoff contract: bypass ring stores
// drained (vmcnt 0) BEFORE the flag store; ring reads issued AFTER exit.
__device__ __forceinline__ void gbar(unsigned* flg, unsigned& bseq, int w, int tid) {
    ++bseq;
    __syncthreads();                                  // all waves done (vmcnt drained by compiler)
    if (tid == 0) st4_cc(flg + w * 16, bseq);
    if (tid < 128) {
        while (ld4_cc(flg + tid * 16) < bseq) __builtin_amdgcn_s_sleep(1);
    }
    __syncthreads();
}
// Full-fence variant (L2 writeback + invalidate): ONLY at init and at the
// layer 0 -> 1 boundary (publishes cached y0b, clears layer-0 ring lines).
__device__ __forceinline__ void gbar_full(unsigned* flg, unsigned& bseq, int w, int tid) {
    ++bseq;
    __syncthreads();
    if (tid == 0) { __threadfence(); st4_cc(flg + w * 16, bseq); }   // release: wb L2
    if (tid < 128) {
        while (ld4_cc(flg + tid * 16) < bseq) __builtin_amdgcn_s_sleep(1);
    }
    __syncthreads();
    if (tid == 0) __threadfence();                    // acquire: inv L1/L2
    __syncthreads();
}

// ---------------- GEMM half-slice: z[64x32] += A[64x1024] * Wlds[1024x32] ----------------
// A: normal cached global loads (xb / y0b / h-ring), depth-1 group-of-4
// prefetch.  B: LDS (ds_read_b128, ~12cy) -> zero per-step weight fabric
// traffic, B off the vmcnt chain entirely.
__device__ __forceinline__ void gemm_half(const unsigned short* __restrict__ a0p,
                                          const unsigned short* __restrict__ a1p,
                                          const short8* __restrict__ lb,
                                          f32x4& c00, f32x4& c01, f32x4& c10, f32x4& c11) {
    short8 A0[2][4], A1[2][4];
#pragma unroll
    for (int i = 0; i < 4; ++i) {
        A0[0][i] = *(const short8*)(a0p + i * 2048);
        A1[0][i] = *(const short8*)(a1p + i * 2048);
    }
#pragma unroll
    for (int g = 0; g < 8; ++g) {
        const int cur = g & 1, nxt = cur ^ 1;   // static after full unroll (rule #20 ok)
        if (g < 7) {
#pragma unroll
            for (int i = 0; i < 4; ++i) {
                const int s = (g + 1) * 4 + i;
                A0[nxt][i] = *(const short8*)(a0p + s * 2048);
                A1[nxt][i] = *(const short8*)(a1p + s * 2048);
            }
        }
#pragma unroll
        for (int i = 0; i < 4; ++i) {
            const int s = g * 4 + i;
            short8 bf0 = lb[s * 128];        // kb += 4 per s -> +128 16B-units
            short8 bf1 = lb[s * 128 + 16];   // +16 cols
            c00 = __builtin_amdgcn_mfma_f32_16x16x32_bf16(A0[cur][i], bf0, c00, 0, 0, 0);
            c01 = __builtin_amdgcn_mfma_f32_16x16x32_bf16(A0[cur][i], bf1, c01, 0, 0, 0);
            c10 = __builtin_amdgcn_mfma_f32_16x16x32_bf16(A1[cur][i], bf0, c10, 0, 0, 0);
            c11 = __builtin_amdgcn_mfma_f32_16x16x32_bf16(A1[cur][i], bf1, c11, 0, 0, 0);
        }
    }
}

// ---------------- persistent LSTM loop ----------------
// xb    : [t][kb 0..127][b][8] bf16   (layer-0 x part of A; cached)
// y0b   : same layout, layer-0 outputs (layer-1 x part; published at boundary)
// hring : 513 slots x [kb2 0..127][b][8] bf16.  Slot t = h-state INPUT of
//         step t.  WRITE-ONCE addresses: slot t+1 written (sc0 sc1, never
//         cached dirty) during step t, read (normal cached) only after the
//         step-t barrier -> no L1/L2 can hold a stale copy; 16 WGs/XCD share
//         the L2 fill (16x fabric dedup).  Layer 1 reuses slots: the
//         boundary gbar_full invalidate clears layer-0 cached copies first.
// cst   : [2 layers][j 0..1023][b] f32  (WG-private, cached)
__launch_bounds__(NTHR, 1)
__global__ void lstm_loop(const unsigned short* __restrict__ xb,
                          unsigned short* __restrict__ y0b,
                          const unsigned short* __restrict__ wc0,
                          const unsigned short* __restrict__ wc1,
                          const float* __restrict__ pb,
                          const int* __restrict__ lens,
                          unsigned short* __restrict__ hring,
                          float* __restrict__ cst,
                          unsigned* __restrict__ flg,
                          float* __restrict__ out) {
    extern __shared__ short8 lwc[];     // 131072 B: this WG's weight slice [kb(256)][n(32)] 16B units
    __shared__ float zbuf[2][64][33];   // [k-half][b][col32], +1 pad vs bank conflicts
    __shared__ float pbl[2][32];
    __shared__ __align__(16) unsigned short hsh[64][8];   // h staging: 256 ushort -> 64 dwordx4 stores

    const int w = blockIdx.x;
    const int tid = threadIdx.x;
    const int lane = tid & 63;
    const int wave = tid >> 6;
    const int m  = wave & 1;     // M-pair: rows [m*32, m*32+32)
    const int kh = wave >> 1;    // K-half: 0 = x part, 1 = h part
    const int q16 = lane >> 4;
    const int n16 = lane & 15;

    // ---- per-launch init (ws is re-poisoned every launch) ----
    st4_cc((unsigned*)hring + w * 256 + tid, 0u);             // zero ring slot 0 (bypass)
    {
        int ly = tid >> 7, r = tid & 127;                     // zero c state rows [8w,8w+8), both layers
        ((float4*)(cst + ly * 65536 + w * 512))[r] = make_float4(0.f, 0.f, 0.f, 0.f);
    }
    if (tid < 64) pbl[tid >> 5][tid & 31] = pb[((tid >> 5) * 128 + w) * 32 + (tid & 31)];
    const int lenb = lens[tid & 63];
    drain_vm();                                               // slot-0 zeros at LLC before anyone reads
    unsigned bseq = 0;
    gbar_full(flg, bseq, w, tid);

    for (int layer = 0; layer < 2; ++layer) {
        const unsigned short* xsrc = layer ? y0b : xb;
        const unsigned short* wc   = layer ? wc1 : wc0;

        // ---- stage this layer's 128 KB weight slice into LDS (once) ----
        {
            const short8* gsrc = (const short8*)(wc + (size_t)w * 65536);
#pragma unroll 4
            for (int i = 0; i < 32; ++i) lwc[tid + i * 256] = gsrc[tid + i * 256];
        }
        __syncthreads();

        // lane's B base in LDS: element (kb*32 + n), kb = kh*128 + q16 (+4 per s)
        const short8* lb = lwc + (kh * 128 + q16) * 32 + n16;

        float hpf[2] = {0.f, 0.f};   // this thread's own h(b, jj)/h(b, jj+4): hold-state source
        for (int t = 0; t < Tsz; ++t) {
            // ---- GEMM: z[64 x 32cols] += A[64 x 1024(kh)] * W[1024 x 32] ----
            f32x4 c00 = {0.f,0.f,0.f,0.f}, c01 = {0.f,0.f,0.f,0.f};
            f32x4 c10 = {0.f,0.f,0.f,0.f}, c11 = {0.f,0.f,0.f,0.f};
            const unsigned short* Abase = (kh == 0) ? (xsrc  + (size_t)t * 65536)
                                                    : (hring + (size_t)t * 65536);
            const unsigned short* a0p = Abase + (q16 * 64 + m * 32 + n16) * 8;
            const unsigned short* a1p = a0p + 128;                     // +16 rows
            gemm_half(a0p, a1p, lb, c00, c01, c10, c11);
            {
                const int rowb = m * 32 + q16 * 4;
#pragma unroll
                for (int r = 0; r < 4; ++r) {
                    zbuf[kh][rowb + r][n16]           = c00[r];
                    zbuf[kh][rowb + r][n16 + 16]      = c01[r];
                    zbuf[kh][rowb + 16 + r][n16]      = c10[r];
                    zbuf[kh][rowb + 16 + r][n16 + 16] = c11[r];
                }
            }
            __syncthreads();

            // ---- elementwise gates + state update (this WG owns j = 8w..8w+7) ----
            const int b = tid & 63;
            const bool active = (t < lenb);
#pragma unroll
            for (int h2 = 0; h2 < 2; ++h2) {
                const int jj = wave + h2 * 4;
                const int nt = jj >> 2, qq = jj & 3;
                const int cb = nt * 16 + qq;
                float zi = zbuf[0][b][cb]      + zbuf[1][b][cb]      + pbl[layer][cb];
                float zc = zbuf[0][b][cb + 4]  + zbuf[1][b][cb + 4]  + pbl[layer][cb + 4];
                float zf = zbuf[0][b][cb + 8]  + zbuf[1][b][cb + 8]  + pbl[layer][cb + 8];
                float zo = zbuf[0][b][cb + 12] + zbuf[1][b][cb + 12] + pbl[layer][cb + 12];
                if (active) {
                    const int ci = (layer * 1024 + w * 8 + jj) * 64 + b;
                    float c  = cst[ci];
                    float cn = c * sigm(zf + 1.0f) + sigm(zi) * tanh_(zc);
                    cst[ci] = cn;
                    hpf[h2] = tanh_(cn) * sigm(zo);
                }  // inactive: hold hpf (dynamic_rnn state-hold)
                unsigned short hv = f2bf(hpf[h2]);
                hsh[b][jj] = hv;
                const int hi = (w * 64 + b) * 8 + jj;
                if (layer == 0) {
                    y0b[(size_t)t * 65536 + hi] = active ? hv : (unsigned short)0;
                } else {
                    out[(size_t)(b * Tsz + t) * 1024 + w * 8 + jj] = active ? hpf[h2] : 0.0f;
                }
            }
            __syncthreads();   // hsh complete
            if (tid < 64) {    // wave 0: publish this WG's h slice to ring slot t+1 (bypass)
                uintx4 v = ((const uintx4*)hsh)[tid];
                st16_cc((unsigned short*)hring + (size_t)(t + 1) * 65536 + (size_t)w * 512 + (size_t)tid * 8, v);
                drain_vm();    // h at LLC before the flag store (thread 0 is in this wave)
            }
            gbar(flg, bseq, w, tid);
        }
        // ---- final (h, c) stacks: straight from registers / private cst ----
        {
            const int b = tid & 63;
#pragma unroll
            for (int h2 = 0; h2 < 2; ++h2) {
                const int jj = wave + h2 * 4;
                const int j = w * 8 + jj;
                out[33554432 + layer * 65536 + b * 1024 + j]          = hpf[h2];                          // h_stack
                out[33554432 + 131072 + layer * 65536 + b * 1024 + j] = cst[(layer * 1024 + j) * 64 + b]; // c_stack
            }
        }
        if (layer == 0) {
            // re-zero ring slot 0 for layer 1 (bypass, drained), then full-fence
            // barrier: publishes cached y0b AND invalidates layer-0 ring lines.
            st4_cc((unsigned*)hring + w * 256 + tid, 0u);
            drain_vm();
            gbar_full(flg, bseq, w, tid);
        }
    }
}

// ---------------- launcher ----------------
extern "C" void kernel_launch(void* const* d_in, const int* in_sizes, int n_in,
                              void* d_out, int out_size, void* d_ws, size_t ws_size,
                              hipStream_t stream) {
    const float* x    = (const float*)d_in[0];
    const int*   lens = (const int*)d_in[1];     // integer inputs arrive as int32
    const float* W0   = (const float*)d_in[2];
    const float* b0   = (const float*)d_in[3];
    const float* W1   = (const float*)d_in[4];
    const float* b1   = (const float*)d_in[5];
    char* ws = (char*)d_ws;

    unsigned short* xb   = (unsigned short*)(ws);                    //  67,108,864 B
    unsigned short* y0b  = (unsigned short*)(ws + 67108864);         //  67,108,864 B
    unsigned short* wc0  = (unsigned short*)(ws + 134217728);        //  16,777,216 B
    unsigned short* wc1  = (unsigned short*)(ws + 150994944);        //  16,777,216 B
    float*          pb   = (float*)         (ws + 167772160);        //      32,768 B
    float*          cst  = (float*)         (ws + 167804928);        //     524,288 B
    unsigned*       flg  = (unsigned*)      (ws + 168329216);        //       8,192 B
    unsigned short* hrng = (unsigned short*)(ws + 168337408);        //  67,239,936 B (513 slots)
                                                                     //  total ~235.6 MB

    hipLaunchKernelGGL(cast_x,   dim3(16384), dim3(256), 0, stream, x, xb);
    hipLaunchKernelGGL(build_wc, dim3(8192),  dim3(256), 0, stream, W0, W1, wc0, wc1);
    hipLaunchKernelGGL(build_pb, dim3(32),    dim3(256), 0, stream, b0, b1, pb, flg);

    float* out = (float*)d_out;
    void* args[] = { &xb, &y0b, &wc0, &wc1, &pb, &lens, &hrng, &cst, &flg, &out };
    (void)hipLaunchCooperativeKernel((void*)lstm_loop, dim3(NWG), dim3(NTHR), args,
                                     131072 /* dynamic LDS: weight slice */, stream);
}